// Round 14
// baseline (185.493 us; speedup 1.0000x reference)
//
#include <hip/hip_runtime.h>
#include <hip/hip_bf16.h>

#define N_NODES 50000
#define N_EDGES 800000
#define FD 128
#define HD 128
#define KTOT 512
#define NTOT 512
#define NRT 391          // ceil(50000/128)
#define RT_PER_XCD 49    // ceil(391/8)
#define SCAN_BLK 1024
#define NSCAN ((N_NODES + SCAN_BLK - 1) / SCAN_BLK)   // 49

typedef __attribute__((ext_vector_type(8))) short short8v;
typedef __attribute__((ext_vector_type(8))) __bf16 bf16x8;
typedef __attribute__((ext_vector_type(4))) float f32x4;
typedef __attribute__((ext_vector_type(4))) int i32x4;

__device__ __forceinline__ short f2bf(float f) {
  unsigned u = __builtin_bit_cast(unsigned, f);
  unsigned r = (u + 0x7FFFu + ((u >> 16) & 1u)) >> 16;
  return (short)(r & 0xFFFFu);
}
__device__ __forceinline__ float bf2f(short s) {
  return __builtin_bit_cast(float, ((unsigned)(unsigned short)s) << 16);
}
// fast gate math: v_exp_f32 (2^x) + v_rcp_f32, ~1ulp — far below bf16 noise
__device__ __forceinline__ float sigm(float x) {
  return __builtin_amdgcn_rcpf(1.f + __builtin_amdgcn_exp2f(-1.44269504f * x));
}
__device__ __forceinline__ float tanh_(float x) {
  return 1.f - 2.f * __builtin_amdgcn_rcpf(1.f + __builtin_amdgcn_exp2f(2.88539009f * x));
}

// swizzle a logical column c (0..511) within its 64-col block: slot ^= r7
__device__ __forceinline__ int swz_col(int c, int r7) {
  return (c & ~63) | (((((c >> 3) & 7) ^ r7)) << 3) | (c & 7);
}

__device__ __forceinline__ void gload_lds16(const void* g, void* l) {
  __builtin_amdgcn_global_load_lds((const __attribute__((address_space(1))) unsigned int*)g,
                                   (__attribute__((address_space(3))) unsigned int*)l, 16, 0, 0);
}

// pack B (transposed+gate-interleaved+swizzled) + bf16 self-cols of Apack
// + FUSED edge count/rank (rank[e] overlays Apack's agg_x col region:
//   row e>>6, int slot e&63 — bytes 0..255 of the row; untouched by the
//   self-col writes here, consumed by k_fill, overwritten only by k_agg_pack).
__global__ void k_pre(const float* __restrict__ Wx, const float* __restrict__ Wxr,
                      const float* __restrict__ Wh, const float* __restrict__ Whr,
                      const float* __restrict__ x, const float* __restrict__ h,
                      const int* __restrict__ ei,
                      short* __restrict__ BpackT, short* __restrict__ Apack,
                      int* __restrict__ cnt) {
  int gid = blockIdx.x * 256 + threadIdx.x;
  if (gid < N_EDGES) {
    int d = ei[N_EDGES + gid];
    int r = atomicAdd(&cnt[d], 1);
    ((int*)(Apack + (size_t)(gid >> 6) * KTOT))[gid & 63] = r;
  }
  if (gid < NTOT * KTOT) {
    int col = gid >> 9;
    int k = gid & 511;
    int hb = col >> 7, rem = col & 127;
    int wn = rem >> 6, g = (rem >> 4) & 3, hlow = rem & 15;
    int hid = hb * 32 + wn * 16 + hlow;
    int sel = k >> 7, f = k & 127;
    const float* W = (sel == 0) ? Wx : (sel == 1) ? Wxr : (sel == 2) ? Wh : Whr;
    BpackT[col * KTOT + swz_col(k, col & 7)] = f2bf(W[(g * 128 + f) * 128 + hid]);
  }
  if (gid < N_NODES * 32) {
    int half = gid >= N_NODES * 16;       // 0: x, 1: h
    int g2 = gid - half * N_NODES * 16;
    int node = g2 >> 4, s = g2 & 15;      // s: 8-elem slice of the row
    const float* src = (half ? h : x) + (size_t)node * 128 + s * 8;
    f32x4 v0 = *(const f32x4*)(src);
    f32x4 v1 = *(const f32x4*)(src + 4);
    short8v o;
#pragma unroll
    for (int q = 0; q < 4; ++q) { o[q] = f2bf(v0[q]); o[q + 4] = f2bf(v1[q]); }
    int blockbase = 128 + half * 256 + (s >> 3) * 64;
    int slot = (s & 7) ^ (node & 7);
    *(short8v*)(Apack + (size_t)node * KTOT + blockbase + slot * 8) = o;
  }
}

// hierarchical scan: A) per-1024 block sums
__global__ void k_scanA(const int* __restrict__ cnt, int* __restrict__ bsum) {
  int blk = blockIdx.x, t = threadIdx.x;
  int base = blk * SCAN_BLK + t * 4;
  int s = 0;
  if (base + 3 < N_NODES) {
    i32x4 v = *(const i32x4*)(cnt + base);
    s = v.x + v.y + v.z + v.w;
  }
#pragma unroll
  for (int d = 1; d < 64; d <<= 1) s += __shfl_xor(s, d);
  __shared__ int ws[4];
  if ((t & 63) == 0) ws[t >> 6] = s;
  __syncthreads();
  if (t == 0) bsum[blk] = ws[0] + ws[1] + ws[2] + ws[3];
}

// C) each block wave-scans the 49 block sums itself, then block-local
//    exclusive scan + block prefix, vectorized writes
__global__ void k_scanC(const int* __restrict__ cnt, const int* __restrict__ bsum,
                        int* __restrict__ off) {
  __shared__ int sboff[NSCAN];
  int blk = blockIdx.x, t = threadIdx.x;
  if (t < 64) {
    int v = (t < NSCAN) ? bsum[t] : 0;
#pragma unroll
    for (int d = 1; d < 64; d <<= 1) {
      int u = __shfl_up(v, d);
      if (t >= d) v += u;
    }
    if (t < NSCAN) sboff[t] = v;
  }
  __syncthreads();
  int base = blk * SCAN_BLK + t * 4;
  int c0 = 0, c1 = 0, c2 = 0, c3 = 0;
  bool ok = base + 3 < N_NODES;
  if (ok) {
    i32x4 v = *(const i32x4*)(cnt + base);
    c0 = v.x; c1 = v.y; c2 = v.z; c3 = v.w;
  }
  int s = c0 + c1 + c2 + c3;
  int v = s;
#pragma unroll
  for (int d = 1; d < 64; d <<= 1) {
    int u = __shfl_up(v, d);
    if ((t & 63) >= d) v += u;
  }
  __shared__ int wsum[4];
  if ((t & 63) == 63) wsum[t >> 6] = v;
  __syncthreads();
  int wbase = 0;
  for (int w = 0; w < (t >> 6); ++w) wbase += wsum[w];
  int excl = (blk ? sboff[blk - 1] : 0) + wbase + v - s;
  if (ok) {
    i32x4 o = {excl, excl + c0, excl + c0 + c1, excl + c0 + c1 + c2};
    *(i32x4*)(off + base) = o;
  }
  if (blk == 0 && t == 0) off[N_NODES] = N_EDGES;
}

// atomic-free fill: slot = off[dst] + rank[e] (rank read from Apack overlay)
__global__ void k_fill(const int* __restrict__ ei, const int* __restrict__ off,
                       const short* __restrict__ Apack, int* __restrict__ elist) {
  int e = blockIdx.x * 256 + threadIdx.x;
  if (e < N_EDGES) {
    int d = ei[N_EDGES + e];
    int rk = ((const int*)(Apack + (size_t)(e >> 6) * KTOT))[e & 63];
    elist[off[d] + rk] = ei[e];
  }
}

// one wave per node, 4 waves/block. PHASED gather (2 source-range phases to
// halve the live L2 working set); bf16 rows from Apack self-columns, 8-deep
// edge unroll; loads exec-masked per phase, adds unconditional (+0 when masked).
__global__ __launch_bounds__(256) void k_agg_pack(const int* __restrict__ off,
                                                  const int* __restrict__ elist,
                                                  short* __restrict__ Apack) {
  int tid = threadIdx.x;
  int node = blockIdx.x * 4 + (tid >> 6);
  int lane = tid & 63;
  int grp = lane >> 4, l4 = lane & 15;
  int is_h = grp & 1, epair = grp >> 1;
  int b = off[node], e = off[node + 1];
  const int cb = is_h * 256 + 128 + (l4 >> 3) * 64;  // self-col 64-block base
  const int sl = l4 & 7;
  float acc[8] = {};
#pragma unroll
  for (int ph = 0; ph < 2; ++ph) {
    const int lo = ph * (N_NODES / 2);
    int j = b;
    for (; j + 8 <= e; j += 8) {
      int s0 = elist[j + epair];
      int s1 = elist[j + 2 + epair];
      int s2 = elist[j + 4 + epair];
      int s3 = elist[j + 6 + epair];
      bool c0 = (unsigned)(s0 - lo) < (unsigned)(N_NODES / 2);
      bool c1 = (unsigned)(s1 - lo) < (unsigned)(N_NODES / 2);
      bool c2 = (unsigned)(s2 - lo) < (unsigned)(N_NODES / 2);
      bool c3 = (unsigned)(s3 - lo) < (unsigned)(N_NODES / 2);
      short8v v0 = (short8v)0, v1 = (short8v)0, v2 = (short8v)0, v3 = (short8v)0;
      if (c0) v0 = *(const short8v*)(Apack + (size_t)s0 * KTOT + cb + ((sl ^ (s0 & 7)) << 3));
      if (c1) v1 = *(const short8v*)(Apack + (size_t)s1 * KTOT + cb + ((sl ^ (s1 & 7)) << 3));
      if (c2) v2 = *(const short8v*)(Apack + (size_t)s2 * KTOT + cb + ((sl ^ (s2 & 7)) << 3));
      if (c3) v3 = *(const short8v*)(Apack + (size_t)s3 * KTOT + cb + ((sl ^ (s3 & 7)) << 3));
#pragma unroll
      for (int q = 0; q < 8; ++q) acc[q] += bf2f(v0[q]);
#pragma unroll
      for (int q = 0; q < 8; ++q) acc[q] += bf2f(v1[q]);
#pragma unroll
      for (int q = 0; q < 8; ++q) acc[q] += bf2f(v2[q]);
#pragma unroll
      for (int q = 0; q < 8; ++q) acc[q] += bf2f(v3[q]);
    }
    for (; j + 2 <= e; j += 2) {
      int s0 = elist[j + epair];
      if ((unsigned)(s0 - lo) < (unsigned)(N_NODES / 2)) {
        short8v v0 = *(const short8v*)(Apack + (size_t)s0 * KTOT + cb + ((sl ^ (s0 & 7)) << 3));
#pragma unroll
        for (int q = 0; q < 8; ++q) acc[q] += bf2f(v0[q]);
      }
    }
    if (j < e && epair == 0) {
      int s0 = elist[j];
      if ((unsigned)(s0 - lo) < (unsigned)(N_NODES / 2)) {
        short8v v0 = *(const short8v*)(Apack + (size_t)s0 * KTOT + cb + ((sl ^ (s0 & 7)) << 3));
#pragma unroll
        for (int q = 0; q < 8; ++q) acc[q] += bf2f(v0[q]);
      }
    }
  }
#pragma unroll
  for (int q = 0; q < 8; ++q) acc[q] += __shfl_xor(acc[q], 32);
  if (grp < 2) {
    float inv = 1.f / (float)max(e - b, 1);
    int cagg = is_h * 256 + (l4 >> 3) * 64 + ((sl ^ (node & 7)) << 3);
    short8v o;
#pragma unroll
    for (int q = 0; q < 8; ++q) o[q] = f2bf(acc[q] * inv);
    *(short8v*)(Apack + (size_t)node * KTOT + cagg) = o;
  }
}

// fused GEMM [50000x512]x[512x512] bf16 MFMA + LSTM epilogue.
// 2-phase dbuf A+B in LDS (64KB), 512 threads / 8 waves as 4M x 2N.
__global__ __launch_bounds__(512, 4) void k_gemm(
    const short* __restrict__ Apack, const short* __restrict__ BpackT,
    const float* __restrict__ c_in, const float* __restrict__ bx, const float* __restrict__ bh,
    const float* __restrict__ fcw,
    float* __restrict__ hnew, float* __restrict__ cnew, float* __restrict__ ypart) {
  __shared__ short As[2][128 * 64];
  __shared__ short Bs[2][128 * 64];
  const int bid = blockIdx.x;
  const int xcd = bid & 7, q = bid >> 3;
  const int rt = xcd * RT_PER_XCD + (q >> 2);
  const int hb = q & 3;
  if (rt >= NRT) return;
  const int tid = threadIdx.x;
  const int wave = tid >> 6, lane = tid & 63;
  const int l15 = lane & 15, lhi = lane >> 4;
  const int wm = wave & 3, wn = wave >> 2;
  const int row0 = rt * 128;

  const short* Abase = Apack + (size_t)row0 * KTOT;
  const short* Bbase = BpackT + (size_t)hb * 128 * KTOT;
  const int stg_r = tid >> 3;        // 0..63 (+64 per it)
  const int stg_s = tid & 7;         // 16B slot in 64-col block
  const int ldst = (tid & ~63) * 8;  // wave-uniform lds base (shorts), +it*4096

  auto stage = [&](int buf, int k0) {
#pragma unroll
    for (int it = 0; it < 2; ++it) {
      int r = stg_r + it * 64;
      gload_lds16(Abase + (size_t)r * KTOT + k0 + stg_s * 8, &As[buf][ldst + it * 4096]);
      gload_lds16(Bbase + (size_t)r * KTOT + k0 + stg_s * 8, &Bs[buf][ldst + it * 4096]);
    }
  };

  // ---- prefetch epilogue operands (latency hides under the K-loop) ----
  const int rbase = row0 + wm * 32 + lhi * 4;      // + m*16 + j
  const int hid = hb * 32 + wn * 16 + l15;         // ONE hid per lane
  float pbi = bx[hid] + bh[hid];
  float pbf = bx[128 + hid] + bh[128 + hid];
  float pbt = bx[256 + hid] + bh[256 + hid];
  float pbo = bx[384 + hid] + bh[384 + hid];
  float pfw = fcw[hid];
  float cpre[2][4];
#pragma unroll
  for (int m = 0; m < 2; ++m)
#pragma unroll
    for (int j = 0; j < 4; ++j) {
      int r = rbase + m * 16 + j;
      cpre[m][j] = (r < N_NODES) ? c_in[(size_t)r * HD + hid] : 0.f;
    }

  f32x4 acc[2][4] = {};

  // ---- 2-phase double-buffered K-loop ----
  stage(0, 0);
  __syncthreads();   // implicit vmcnt(0) drain: buf0 ready for all waves
  int cur = 0;
#pragma unroll
  for (int k0 = 0; k0 < KTOT; k0 += 64) {
    if (k0 + 64 < KTOT) stage(cur ^ 1, k0 + 64);   // issue next tile early
#pragma unroll
    for (int kk = 0; kk < 2; ++kk) {
      short8v a[2], bfr[4];
      const int sl = ((kk << 2) | lhi) ^ (l15 & 7);
#pragma unroll
      for (int m = 0; m < 2; ++m)
        a[m] = *(const short8v*)(&As[cur][(wm * 32 + m * 16 + l15) * 64 + sl * 8]);
#pragma unroll
      for (int n = 0; n < 4; ++n)
        bfr[n] = *(const short8v*)(&Bs[cur][(wn * 64 + n * 16 + l15) * 64 + sl * 8]);
#pragma unroll
      for (int m = 0; m < 2; ++m)
#pragma unroll
        for (int n = 0; n < 4; ++n)
          acc[m][n] = __builtin_amdgcn_mfma_f32_16x16x32_bf16(
              __builtin_bit_cast(bf16x8, a[m]), __builtin_bit_cast(bf16x8, bfr[n]),
              acc[m][n], 0, 0, 0);
    }
    __syncthreads();   // drains next-tile loads (issued before compute) + syncs
    cur ^= 1;
  }

  // epilogue: acc[m][g] reg j -> row = rbase + m*16 + j; gate g for this lane's hid
  float yp[2][4];
#pragma unroll
  for (int m = 0; m < 2; ++m) {
#pragma unroll
    for (int j = 0; j < 4; ++j) {
      int r = rbase + m * 16 + j;
      bool ok = r < N_NODES;
      float ig = sigm(acc[m][0][j] + pbi);
      float fg = sigm(acc[m][1][j] + pbf);
      float tg = tanh_(acc[m][2][j] + pbt);
      float og = sigm(acc[m][3][j] + pbo);
      float cn = fg * cpre[m][j] + ig * tg;
      float hn = og * tanh_(cn);
      if (ok) {
        cnew[(size_t)r * HD + hid] = cn;
        hnew[(size_t)r * HD + hid] = hn;
      }
      yp[m][j] = fmaxf(hn, 0.f) * pfw;
    }
  }
  // l15-reduce (16 hids of this wn half), then cross-wn reduce via dead As LDS
#pragma unroll
  for (int m = 0; m < 2; ++m)
#pragma unroll
    for (int j = 0; j < 4; ++j) {
      float v = yp[m][j];
      v += __shfl_xor(v, 1);
      v += __shfl_xor(v, 2);
      v += __shfl_xor(v, 4);
      v += __shfl_xor(v, 8);
      yp[m][j] = v;
    }
  float* yred = (float*)&As[0][0];   // 128 floats, As dead after K-loop
  if (wn == 1 && l15 == 0) {
#pragma unroll
    for (int m = 0; m < 2; ++m)
#pragma unroll
      for (int j = 0; j < 4; ++j)
        yred[wm * 32 + m * 16 + lhi * 4 + j] = yp[m][j];
  }
  __syncthreads();
  if (wn == 0 && l15 == 0) {
#pragma unroll
    for (int m = 0; m < 2; ++m)
#pragma unroll
      for (int j = 0; j < 4; ++j) {
        int r = rbase + m * 16 + j;
        if (r < N_NODES)
          ypart[hb * N_NODES + r] = yp[m][j] + yred[wm * 32 + m * 16 + lhi * 4 + j];
      }
  }
}

__global__ void k_yfinal(const float* __restrict__ ypart, const float* __restrict__ fcb,
                         float* __restrict__ y) {
  int i = blockIdx.x * 256 + threadIdx.x;
  if (i < N_NODES)
    y[i] = fcb[0] + ypart[i] + ypart[N_NODES + i] + ypart[2 * N_NODES + i] + ypart[3 * N_NODES + i];
}

extern "C" void kernel_launch(void* const* d_in, const int* in_sizes, int n_in,
                              void* d_out, int out_size, void* d_ws, size_t ws_size,
                              hipStream_t stream) {
  const float* x   = (const float*)d_in[0];
  const int*   ei  = (const int*)d_in[1];
  const float* h   = (const float*)d_in[3];
  const float* c   = (const float*)d_in[4];
  const float* Wx  = (const float*)d_in[5];
  const float* Wxr = (const float*)d_in[6];
  const float* bx  = (const float*)d_in[7];
  const float* Wh  = (const float*)d_in[8];
  const float* Whr = (const float*)d_in[9];
  const float* bh  = (const float*)d_in[10];
  const float* fcw = (const float*)d_in[11];
  const float* fcb = (const float*)d_in[12];

  float* y    = (float*)d_out;
  float* hnew = y + N_NODES;
  float* cnew = hnew + (size_t)N_NODES * HD;

  char* w = (char*)d_ws;
  auto carve = [&](size_t bytes) {
    char* p = w;
    w += (bytes + 255) & ~(size_t)255;
    return p;
  };
  // EXACT round-4 footprint (proven to fit ws_size). Overlays:
  //   bsum -> ypart (dead before k_gemm writes ypart)
  //   rank -> Apack agg_x col region (row e>>6, int e&63): written by k_pre,
  //           read by k_fill, overwritten only later by k_agg_pack
  int* cnt      = (int*)carve((size_t)N_NODES * 4);
  int* off      = (int*)carve((size_t)(N_NODES + 1) * 4);
  int* pos      = (int*)carve((size_t)N_NODES * 4);   // unused (layout keeper)
  int* elist    = (int*)carve((size_t)N_EDGES * 4);
  short* Apack  = (short*)carve((size_t)N_NODES * KTOT * 2);
  short* BpackT = (short*)carve((size_t)NTOT * KTOT * 2);
  float* ypart  = (float*)carve((size_t)4 * N_NODES * 4);
  int* bsum     = (int*)ypart;        // 49 ints, dead before k_gemm
  (void)pos;

  hipMemsetAsync(cnt, 0, (size_t)N_NODES * 4, stream);
  k_pre<<<(N_NODES * 32 + 255) / 256, 256, 0, stream>>>(Wx, Wxr, Wh, Whr, x, h, ei,
                                                        BpackT, Apack, cnt);
  k_scanA<<<NSCAN, 256, 0, stream>>>(cnt, bsum);
  k_scanC<<<NSCAN, 256, 0, stream>>>(cnt, bsum, off);
  k_fill<<<(N_EDGES + 255) / 256, 256, 0, stream>>>(ei, off, Apack, elist);
  k_agg_pack<<<(N_NODES + 3) / 4, 256, 0, stream>>>(off, elist, Apack);
  dim3 gg(8 * RT_PER_XCD * 4);
  k_gemm<<<gg, 512, 0, stream>>>(Apack, BpackT, c, bx, bh, fcw, hnew, cnew, ypart);
  k_yfinal<<<(N_NODES + 255) / 256, 256, 0, stream>>>(ypart, fcb, y);
}

// Round 15
// 170.832 us; speedup vs baseline: 1.0858x; 1.0858x over previous
//
#include <hip/hip_runtime.h>
#include <hip/hip_bf16.h>

#define N_NODES 50000
#define N_EDGES 800000
#define FD 128
#define HD 128
#define KTOT 512
#define NTOT 512
#define NRT 391          // ceil(50000/128)
#define RT_PER_XCD 49    // ceil(391/8)
#define SCAN_BLK 1024
#define NSCAN ((N_NODES + SCAN_BLK - 1) / SCAN_BLK)   // 49

typedef __attribute__((ext_vector_type(8))) short short8v;
typedef __attribute__((ext_vector_type(8))) __bf16 bf16x8;
typedef __attribute__((ext_vector_type(4))) float f32x4;
typedef __attribute__((ext_vector_type(4))) int i32x4;

__device__ __forceinline__ short f2bf(float f) {
  unsigned u = __builtin_bit_cast(unsigned, f);
  unsigned r = (u + 0x7FFFu + ((u >> 16) & 1u)) >> 16;
  return (short)(r & 0xFFFFu);
}
__device__ __forceinline__ float bf2f(short s) {
  return __builtin_bit_cast(float, ((unsigned)(unsigned short)s) << 16);
}
// fast gate math: v_exp_f32 (2^x) + v_rcp_f32, ~1ulp — far below bf16 noise
__device__ __forceinline__ float sigm(float x) {
  return __builtin_amdgcn_rcpf(1.f + __builtin_amdgcn_exp2f(-1.44269504f * x));
}
__device__ __forceinline__ float tanh_(float x) {
  return 1.f - 2.f * __builtin_amdgcn_rcpf(1.f + __builtin_amdgcn_exp2f(2.88539009f * x));
}

// swizzle a logical column c (0..511) within its 64-col block: slot ^= r7
__device__ __forceinline__ int swz_col(int c, int r7) {
  return (c & ~63) | (((((c >> 3) & 7) ^ r7)) << 3) | (c & 7);
}

__device__ __forceinline__ void gload_lds16(const void* g, void* l) {
  __builtin_amdgcn_global_load_lds((const __attribute__((address_space(1))) unsigned int*)g,
                                   (__attribute__((address_space(3))) unsigned int*)l, 16, 0, 0);
}

// pack B (transposed+gate-interleaved+swizzled) + bf16 self-cols of Apack
// + FUSED edge count/rank (rank[e] overlays Apack's agg_x col region:
//   row e>>6, int slot e&63 — bytes 0..255 of the row; untouched by the
//   self-col writes here, consumed by k_fill, overwritten only by k_agg_pack).
__global__ void k_pre(const float* __restrict__ Wx, const float* __restrict__ Wxr,
                      const float* __restrict__ Wh, const float* __restrict__ Whr,
                      const float* __restrict__ x, const float* __restrict__ h,
                      const int* __restrict__ ei,
                      short* __restrict__ BpackT, short* __restrict__ Apack,
                      int* __restrict__ cnt) {
  int gid = blockIdx.x * 256 + threadIdx.x;
  if (gid < N_EDGES) {
    int d = ei[N_EDGES + gid];
    int r = atomicAdd(&cnt[d], 1);
    ((int*)(Apack + (size_t)(gid >> 6) * KTOT))[gid & 63] = r;
  }
  if (gid < NTOT * KTOT) {
    int col = gid >> 9;
    int k = gid & 511;
    int hb = col >> 7, rem = col & 127;
    int wn = rem >> 6, g = (rem >> 4) & 3, hlow = rem & 15;
    int hid = hb * 32 + wn * 16 + hlow;
    int sel = k >> 7, f = k & 127;
    const float* W = (sel == 0) ? Wx : (sel == 1) ? Wxr : (sel == 2) ? Wh : Whr;
    BpackT[col * KTOT + swz_col(k, col & 7)] = f2bf(W[(g * 128 + f) * 128 + hid]);
  }
  if (gid < N_NODES * 32) {
    int half = gid >= N_NODES * 16;       // 0: x, 1: h
    int g2 = gid - half * N_NODES * 16;
    int node = g2 >> 4, s = g2 & 15;      // s: 8-elem slice of the row
    const float* src = (half ? h : x) + (size_t)node * 128 + s * 8;
    f32x4 v0 = *(const f32x4*)(src);
    f32x4 v1 = *(const f32x4*)(src + 4);
    short8v o;
#pragma unroll
    for (int q = 0; q < 4; ++q) { o[q] = f2bf(v0[q]); o[q + 4] = f2bf(v1[q]); }
    int blockbase = 128 + half * 256 + (s >> 3) * 64;
    int slot = (s & 7) ^ (node & 7);
    *(short8v*)(Apack + (size_t)node * KTOT + blockbase + slot * 8) = o;
  }
}

// hierarchical scan: A) per-1024 block sums
__global__ void k_scanA(const int* __restrict__ cnt, int* __restrict__ bsum) {
  int blk = blockIdx.x, t = threadIdx.x;
  int base = blk * SCAN_BLK + t * 4;
  int s = 0;
  if (base + 3 < N_NODES) {
    i32x4 v = *(const i32x4*)(cnt + base);
    s = v.x + v.y + v.z + v.w;
  }
#pragma unroll
  for (int d = 1; d < 64; d <<= 1) s += __shfl_xor(s, d);
  __shared__ int ws[4];
  if ((t & 63) == 0) ws[t >> 6] = s;
  __syncthreads();
  if (t == 0) bsum[blk] = ws[0] + ws[1] + ws[2] + ws[3];
}

// C) each block wave-scans the 49 block sums itself, then block-local
//    exclusive scan + block prefix, vectorized writes
__global__ void k_scanC(const int* __restrict__ cnt, const int* __restrict__ bsum,
                        int* __restrict__ off) {
  __shared__ int sboff[NSCAN];
  int blk = blockIdx.x, t = threadIdx.x;
  if (t < 64) {
    int v = (t < NSCAN) ? bsum[t] : 0;
#pragma unroll
    for (int d = 1; d < 64; d <<= 1) {
      int u = __shfl_up(v, d);
      if (t >= d) v += u;
    }
    if (t < NSCAN) sboff[t] = v;
  }
  __syncthreads();
  int base = blk * SCAN_BLK + t * 4;
  int c0 = 0, c1 = 0, c2 = 0, c3 = 0;
  bool ok = base + 3 < N_NODES;
  if (ok) {
    i32x4 v = *(const i32x4*)(cnt + base);
    c0 = v.x; c1 = v.y; c2 = v.z; c3 = v.w;
  }
  int s = c0 + c1 + c2 + c3;
  int v = s;
#pragma unroll
  for (int d = 1; d < 64; d <<= 1) {
    int u = __shfl_up(v, d);
    if ((t & 63) >= d) v += u;
  }
  __shared__ int wsum[4];
  if ((t & 63) == 63) wsum[t >> 6] = v;
  __syncthreads();
  int wbase = 0;
  for (int w = 0; w < (t >> 6); ++w) wbase += wsum[w];
  int excl = (blk ? sboff[blk - 1] : 0) + wbase + v - s;
  if (ok) {
    i32x4 o = {excl, excl + c0, excl + c0 + c1, excl + c0 + c1 + c2};
    *(i32x4*)(off + base) = o;
  }
  if (blk == 0 && t == 0) off[N_NODES] = N_EDGES;
}

// atomic-free fill: slot = off[dst] + rank[e] (rank read from Apack overlay)
__global__ void k_fill(const int* __restrict__ ei, const int* __restrict__ off,
                       const short* __restrict__ Apack, int* __restrict__ elist) {
  int e = blockIdx.x * 256 + threadIdx.x;
  if (e < N_EDGES) {
    int d = ei[N_EDGES + e];
    int rk = ((const int*)(Apack + (size_t)(e >> 6) * KTOT))[e & 63];
    elist[off[d] + rk] = ei[e];
  }
}

// one wave per node, 4 waves/block. Gather bf16 rows from Apack's self-columns
// (8-deep edge unroll: 4 independent 16B loads in flight per lane-group).
__global__ __launch_bounds__(256) void k_agg_pack(const int* __restrict__ off,
                                                  const int* __restrict__ elist,
                                                  short* __restrict__ Apack) {
  int tid = threadIdx.x;
  int node = blockIdx.x * 4 + (tid >> 6);
  int lane = tid & 63;
  int grp = lane >> 4, l4 = lane & 15;
  int is_h = grp & 1, epair = grp >> 1;
  int b = off[node], e = off[node + 1];
  const int cb = is_h * 256 + 128 + (l4 >> 3) * 64;  // self-col 64-block base
  const int sl = l4 & 7;
  float acc[8] = {};
  int j = b;
  for (; j + 8 <= e; j += 8) {
    int s0 = elist[j + epair];
    int s1 = elist[j + 2 + epair];
    int s2 = elist[j + 4 + epair];
    int s3 = elist[j + 6 + epair];
    short8v v0 = *(const short8v*)(Apack + (size_t)s0 * KTOT + cb + ((sl ^ (s0 & 7)) << 3));
    short8v v1 = *(const short8v*)(Apack + (size_t)s1 * KTOT + cb + ((sl ^ (s1 & 7)) << 3));
    short8v v2 = *(const short8v*)(Apack + (size_t)s2 * KTOT + cb + ((sl ^ (s2 & 7)) << 3));
    short8v v3 = *(const short8v*)(Apack + (size_t)s3 * KTOT + cb + ((sl ^ (s3 & 7)) << 3));
#pragma unroll
    for (int q = 0; q < 8; ++q) acc[q] += bf2f(v0[q]);
#pragma unroll
    for (int q = 0; q < 8; ++q) acc[q] += bf2f(v1[q]);
#pragma unroll
    for (int q = 0; q < 8; ++q) acc[q] += bf2f(v2[q]);
#pragma unroll
    for (int q = 0; q < 8; ++q) acc[q] += bf2f(v3[q]);
  }
  for (; j + 2 <= e; j += 2) {
    int s0 = elist[j + epair];
    short8v v0 = *(const short8v*)(Apack + (size_t)s0 * KTOT + cb + ((sl ^ (s0 & 7)) << 3));
#pragma unroll
    for (int q = 0; q < 8; ++q) acc[q] += bf2f(v0[q]);
  }
  if (j < e && epair == 0) {
    int s0 = elist[j];
    short8v v0 = *(const short8v*)(Apack + (size_t)s0 * KTOT + cb + ((sl ^ (s0 & 7)) << 3));
#pragma unroll
    for (int q = 0; q < 8; ++q) acc[q] += bf2f(v0[q]);
  }
#pragma unroll
  for (int q = 0; q < 8; ++q) acc[q] += __shfl_xor(acc[q], 32);
  if (grp < 2) {
    float inv = 1.f / (float)max(e - b, 1);
    int cagg = is_h * 256 + (l4 >> 3) * 64 + ((sl ^ (node & 7)) << 3);
    short8v o;
#pragma unroll
    for (int q = 0; q < 8; ++q) o[q] = f2bf(acc[q] * inv);
    *(short8v*)(Apack + (size_t)node * KTOT + cagg) = o;
  }
}

// fused GEMM [50000x512]x[512x512] bf16 MFMA + LSTM epilogue.
// 2-phase dbuf A+B in LDS (64KB), 512 threads / 8 waves as 4M x 2N.
__global__ __launch_bounds__(512, 4) void k_gemm(
    const short* __restrict__ Apack, const short* __restrict__ BpackT,
    const float* __restrict__ c_in, const float* __restrict__ bx, const float* __restrict__ bh,
    const float* __restrict__ fcw,
    float* __restrict__ hnew, float* __restrict__ cnew, float* __restrict__ ypart) {
  __shared__ short As[2][128 * 64];
  __shared__ short Bs[2][128 * 64];
  const int bid = blockIdx.x;
  const int xcd = bid & 7, q = bid >> 3;
  const int rt = xcd * RT_PER_XCD + (q >> 2);
  const int hb = q & 3;
  if (rt >= NRT) return;
  const int tid = threadIdx.x;
  const int wave = tid >> 6, lane = tid & 63;
  const int l15 = lane & 15, lhi = lane >> 4;
  const int wm = wave & 3, wn = wave >> 2;
  const int row0 = rt * 128;

  const short* Abase = Apack + (size_t)row0 * KTOT;
  const short* Bbase = BpackT + (size_t)hb * 128 * KTOT;
  const int stg_r = tid >> 3;        // 0..63 (+64 per it)
  const int stg_s = tid & 7;         // 16B slot in 64-col block
  const int ldst = (tid & ~63) * 8;  // wave-uniform lds base (shorts), +it*4096

  auto stage = [&](int buf, int k0) {
#pragma unroll
    for (int it = 0; it < 2; ++it) {
      int r = stg_r + it * 64;
      gload_lds16(Abase + (size_t)r * KTOT + k0 + stg_s * 8, &As[buf][ldst + it * 4096]);
      gload_lds16(Bbase + (size_t)r * KTOT + k0 + stg_s * 8, &Bs[buf][ldst + it * 4096]);
    }
  };

  // ---- prefetch epilogue operands (latency hides under the K-loop) ----
  const int rbase = row0 + wm * 32 + lhi * 4;      // + m*16 + j
  const int hid = hb * 32 + wn * 16 + l15;         // ONE hid per lane
  float pbi = bx[hid] + bh[hid];
  float pbf = bx[128 + hid] + bh[128 + hid];
  float pbt = bx[256 + hid] + bh[256 + hid];
  float pbo = bx[384 + hid] + bh[384 + hid];
  float pfw = fcw[hid];
  float cpre[2][4];
#pragma unroll
  for (int m = 0; m < 2; ++m)
#pragma unroll
    for (int j = 0; j < 4; ++j) {
      int r = rbase + m * 16 + j;
      cpre[m][j] = (r < N_NODES) ? c_in[(size_t)r * HD + hid] : 0.f;
    }

  f32x4 acc[2][4] = {};

  // ---- 2-phase double-buffered K-loop ----
  stage(0, 0);
  __syncthreads();   // implicit vmcnt(0) drain: buf0 ready for all waves
  int cur = 0;
#pragma unroll
  for (int k0 = 0; k0 < KTOT; k0 += 64) {
    if (k0 + 64 < KTOT) stage(cur ^ 1, k0 + 64);   // issue next tile early
#pragma unroll
    for (int kk = 0; kk < 2; ++kk) {
      short8v a[2], bfr[4];
      const int sl = ((kk << 2) | lhi) ^ (l15 & 7);
#pragma unroll
      for (int m = 0; m < 2; ++m)
        a[m] = *(const short8v*)(&As[cur][(wm * 32 + m * 16 + l15) * 64 + sl * 8]);
#pragma unroll
      for (int n = 0; n < 4; ++n)
        bfr[n] = *(const short8v*)(&Bs[cur][(wn * 64 + n * 16 + l15) * 64 + sl * 8]);
#pragma unroll
      for (int m = 0; m < 2; ++m)
#pragma unroll
        for (int n = 0; n < 4; ++n)
          acc[m][n] = __builtin_amdgcn_mfma_f32_16x16x32_bf16(
              __builtin_bit_cast(bf16x8, a[m]), __builtin_bit_cast(bf16x8, bfr[n]),
              acc[m][n], 0, 0, 0);
    }
    __syncthreads();   // drains next-tile loads (issued before compute) + syncs
    cur ^= 1;
  }

  // epilogue: acc[m][g] reg j -> row = rbase + m*16 + j; gate g for this lane's hid
  float yp[2][4];
#pragma unroll
  for (int m = 0; m < 2; ++m) {
#pragma unroll
    for (int j = 0; j < 4; ++j) {
      int r = rbase + m * 16 + j;
      bool ok = r < N_NODES;
      float ig = sigm(acc[m][0][j] + pbi);
      float fg = sigm(acc[m][1][j] + pbf);
      float tg = tanh_(acc[m][2][j] + pbt);
      float og = sigm(acc[m][3][j] + pbo);
      float cn = fg * cpre[m][j] + ig * tg;
      float hn = og * tanh_(cn);
      if (ok) {
        cnew[(size_t)r * HD + hid] = cn;
        hnew[(size_t)r * HD + hid] = hn;
      }
      yp[m][j] = fmaxf(hn, 0.f) * pfw;
    }
  }
  // l15-reduce (16 hids of this wn half), then cross-wn reduce via dead As LDS
#pragma unroll
  for (int m = 0; m < 2; ++m)
#pragma unroll
    for (int j = 0; j < 4; ++j) {
      float v = yp[m][j];
      v += __shfl_xor(v, 1);
      v += __shfl_xor(v, 2);
      v += __shfl_xor(v, 4);
      v += __shfl_xor(v, 8);
      yp[m][j] = v;
    }
  float* yred = (float*)&As[0][0];   // 128 floats, As dead after K-loop
  if (wn == 1 && l15 == 0) {
#pragma unroll
    for (int m = 0; m < 2; ++m)
#pragma unroll
      for (int j = 0; j < 4; ++j)
        yred[wm * 32 + m * 16 + lhi * 4 + j] = yp[m][j];
  }
  __syncthreads();
  if (wn == 0 && l15 == 0) {
#pragma unroll
    for (int m = 0; m < 2; ++m)
#pragma unroll
      for (int j = 0; j < 4; ++j) {
        int r = rbase + m * 16 + j;
        if (r < N_NODES)
          ypart[hb * N_NODES + r] = yp[m][j] + yred[wm * 32 + m * 16 + lhi * 4 + j];
      }
  }
}

__global__ void k_yfinal(const float* __restrict__ ypart, const float* __restrict__ fcb,
                         float* __restrict__ y) {
  int i = blockIdx.x * 256 + threadIdx.x;
  if (i < N_NODES)
    y[i] = fcb[0] + ypart[i] + ypart[N_NODES + i] + ypart[2 * N_NODES + i] + ypart[3 * N_NODES + i];
}

extern "C" void kernel_launch(void* const* d_in, const int* in_sizes, int n_in,
                              void* d_out, int out_size, void* d_ws, size_t ws_size,
                              hipStream_t stream) {
  const float* x   = (const float*)d_in[0];
  const int*   ei  = (const int*)d_in[1];
  const float* h   = (const float*)d_in[3];
  const float* c   = (const float*)d_in[4];
  const float* Wx  = (const float*)d_in[5];
  const float* Wxr = (const float*)d_in[6];
  const float* bx  = (const float*)d_in[7];
  const float* Wh  = (const float*)d_in[8];
  const float* Whr = (const float*)d_in[9];
  const float* bh  = (const float*)d_in[10];
  const float* fcw = (const float*)d_in[11];
  const float* fcb = (const float*)d_in[12];

  float* y    = (float*)d_out;
  float* hnew = y + N_NODES;
  float* cnew = hnew + (size_t)N_NODES * HD;

  char* w = (char*)d_ws;
  auto carve = [&](size_t bytes) {
    char* p = w;
    w += (bytes + 255) & ~(size_t)255;
    return p;
  };
  // EXACT round-4 footprint (proven to fit ws_size). Overlays:
  //   bsum -> ypart (dead before k_gemm writes ypart)
  //   rank -> Apack agg_x col region (row e>>6, int e&63): written by k_pre,
  //           read by k_fill, overwritten only later by k_agg_pack
  int* cnt      = (int*)carve((size_t)N_NODES * 4);
  int* off      = (int*)carve((size_t)(N_NODES + 1) * 4);
  int* pos      = (int*)carve((size_t)N_NODES * 4);   // unused (layout keeper)
  int* elist    = (int*)carve((size_t)N_EDGES * 4);
  short* Apack  = (short*)carve((size_t)N_NODES * KTOT * 2);
  short* BpackT = (short*)carve((size_t)NTOT * KTOT * 2);
  float* ypart  = (float*)carve((size_t)4 * N_NODES * 4);
  int* bsum     = (int*)ypart;        // 49 ints, dead before k_gemm
  (void)pos;

  hipMemsetAsync(cnt, 0, (size_t)N_NODES * 4, stream);
  k_pre<<<(N_NODES * 32 + 255) / 256, 256, 0, stream>>>(Wx, Wxr, Wh, Whr, x, h, ei,
                                                        BpackT, Apack, cnt);
  k_scanA<<<NSCAN, 256, 0, stream>>>(cnt, bsum);
  k_scanC<<<NSCAN, 256, 0, stream>>>(cnt, bsum, off);
  k_fill<<<(N_EDGES + 255) / 256, 256, 0, stream>>>(ei, off, Apack, elist);
  k_agg_pack<<<(N_NODES + 3) / 4, 256, 0, stream>>>(off, elist, Apack);
  dim3 gg(8 * RT_PER_XCD * 4);
  k_gemm<<<gg, 512, 0, stream>>>(Apack, BpackT, c, bx, bh, fcw, hnew, cnew, ypart);
  k_yfinal<<<(N_NODES + 255) / 256, 256, 0, stream>>>(ypart, fcb, y);
}